// Round 6
// baseline (79.748 us; speedup 1.0000x reference)
//
#include <hip/hip_runtime.h>

// ECT layer: ect[b,s,t] = sum_{n in graph b} sigmoid(500*(lin[s] - x[n,:]@v[:,t]))
// N=50000, F=3, T=64, S=64, B=128.
//
// Cumulative-histogram formulation: sigmoid saturates to 0/1 beyond 0.5 bins
// of c = round((nh+1)*31.5) (err <= 3.6e-4/term), so per (node,t) only
//   hist[c] += sig_c ; hist[c+1] += 1-sig_c ; out[s] = prefix_sum(hist)[s].
// 8 wave-PRIVATE hist[66][64] copies in LDS (rows 64,65 = dump bins): lane=t,
// private copy per wave -> plain ds_read/add/ds_write, NO atomics anywhere
// (r1-r4 lesson: LDS/global atomic pipe was every previous bottleneck).
//
// r5 lesson: kernel time is now ~an order below the harness's fixed ~55us
// re-poison floor (268MB 0xAA ws fill = 40us @84% HBM peak, + restores/gaps).
// This round trims the last kernel-side fat:
//   * bounds kernel FUSED in: dual interleaved binary search (2 independent
//     load chains overlap; partially hidden under LDS zero-init). 1 dispatch.
//   * paired node processing: 2 nodes per wave-iter halves the number of
//     latency-exposed LDS RMW round trips; in-pair (c,t) collisions are
//     compensated exactly (write A first, B last with A's aliased q folded in).
//   * pair x-rows = 6 contiguous floats -> one s_load_dwordx4 + dwordx2.

#define WAVES   8
#define THREADS (WAVES * 64)
#define HR      66   // hist rows: 0..63 real, 64 & 65 dump bins

__global__ __launch_bounds__(THREADS) void ect_fused_kernel(
    const float* __restrict__ x,     // (N,3)
    const float* __restrict__ v,     // (3,64)
    const int*  __restrict__ batch,  // (N) sorted ascending in [0,B)
    float* __restrict__ out,         // (B,64,64)
    int N, int B)
{
    const float KSH   = 721.3475204444817f;   // 500 / ln(2)
    const float KSTEP = 22.900032395062912f;  // KSH * 2/63

    __shared__ float hist[WAVES][HR * 64];    // 135168 B
    __shared__ float stripsum[WAVES][64];     // 137216 B total <= 160KB

    // zero all private hists (independent work to hide search latency under)
    {
        float4* hz = (float4*)&hist[0][0];
        const int nf4 = WAVES * HR * 64 / 4;  // 8448
        for (int i = threadIdx.x; i < nf4; i += THREADS)
            hz[i] = make_float4(0.f, 0.f, 0.f, 0.f);
    }

    const int b = blockIdx.x;

    // dual interleaved binary search: start = lb(b), end = lb(b+1).
    // Two independent dependent-load chains -> latencies overlap.
    int lo1 = 0, hi1 = N, lo2 = 0, hi2 = N;
    while ((lo1 < hi1) || (lo2 < hi2)) {
        if (lo1 < hi1) { const int m = (lo1 + hi1) >> 1;
                         if (batch[m] <  b) lo1 = m + 1; else hi1 = m; }
        if (lo2 < hi2) { const int m = (lo2 + hi2) >> 1;
                         if (batch[m] <= b) lo2 = m + 1; else hi2 = m; }
    }
    const int start = lo1, end = lo2;

    __syncthreads();   // hist zeros visible

    const int t = threadIdx.x & 63;   // theta == lane
    const int w = threadIdx.x >> 6;   // wave id 0..7

    const float vc0 = v[t];
    const float vc1 = v[64 + t];
    const float vc2 = v[128 + t];

    float* H = &hist[w][0];           // this wave's private histogram

    int n = start + w * 2;
#pragma unroll 2
    for (; n + 1 < end; n += 2 * WAVES) {
        const int ns = __builtin_amdgcn_readfirstlane(n);   // wave-uniform -> s_load
        const float xa0 = x[ns * 3 + 0], xa1 = x[ns * 3 + 1], xa2 = x[ns * 3 + 2];
        const float xb0 = x[ns * 3 + 3], xb1 = x[ns * 3 + 4], xb2 = x[ns * 3 + 5];

        const float nhA = xa0 * vc0 + xa1 * vc1 + xa2 * vc2;
        const float nhB = xb0 * vc0 + xb1 * vc1 + xb2 * vc2;

        const float cfA = floorf(fmaf(nhA, 31.5f, 32.0f));  // round((nh+1)*31.5)
        const float cfB = floorf(fmaf(nhB, 31.5f, 32.0f));
        const int   cA  = (int)cfA;
        const int   cB  = (int)cfB;

        // sig = 1/(1+exp2(KSH*nh + KSH - c*KSTEP))
        const float argA = fmaf(-KSTEP, cfA, fmaf(KSH, nhA, KSH));
        const float argB = fmaf(-KSTEP, cfB, fmaf(KSH, nhB, KSH));
        const float sA = __builtin_amdgcn_rcpf(1.0f + __builtin_amdgcn_exp2f(argA));
        const float sB = __builtin_amdgcn_rcpf(1.0f + __builtin_amdgcn_exp2f(argB));

        const int   p1A = min(max(cA, 0), 64);
        const int   p2A = (cA < 0) ? 65 : min(cA + 1, 65);
        const float q1A = (cA < 0) ? 1.0f : ((cA > 63) ? 0.0f : sA);
        const float q2A = ((unsigned)cA <= 63u) ? (1.0f - sA) : 0.0f;

        const int   p1B = min(max(cB, 0), 64);
        const int   p2B = (cB < 0) ? 65 : min(cB + 1, 65);
        const float q1B = (cB < 0) ? 1.0f : ((cB > 63) ? 0.0f : sB);
        const float q2B = ((unsigned)cB <= 63u) ? (1.0f - sB) : 0.0f;

        const int iA1 = p1A * 64 + t, iA2 = p2A * 64 + t;
        const int iB1 = p1B * 64 + t, iB2 = p2B * 64 + t;

        // all 4 reads issue together (one LDS latency), then resolved writes
        const float hA1 = H[iA1], hA2 = H[iA2];
        const float hB1 = H[iB1], hB2 = H[iB2];

        const float wA1 = hA1 + q1A;
        const float wA2 = hA2 + q2A;
        float wB1 = hB1 + q1B;
        float wB2 = hB2 + q2B;
        if (iB1 == iA1) wB1 += q1A;   // fold A's q into any aliased B slot;
        if (iB1 == iA2) wB1 += q2A;   // B writes last, so aliased A writes
        if (iB2 == iA1) wB2 += q1A;   // are overwritten by compensated values
        if (iB2 == iA2) wB2 += q2A;

        H[iA1] = wA1; H[iA2] = wA2;
        H[iB1] = wB1; H[iB2] = wB2;
    }
    if (n < end) {   // tail: single leftover node (n == end-1)
        const int ns = __builtin_amdgcn_readfirstlane(n);
        const float x0 = x[ns * 3 + 0], x1 = x[ns * 3 + 1], x2 = x[ns * 3 + 2];
        const float nh = x0 * vc0 + x1 * vc1 + x2 * vc2;
        const float cf = floorf(fmaf(nh, 31.5f, 32.0f));
        const int   c  = (int)cf;
        const float arg = fmaf(-KSTEP, cf, fmaf(KSH, nh, KSH));
        const float sg  = __builtin_amdgcn_rcpf(1.0f + __builtin_amdgcn_exp2f(arg));
        const int   p1 = min(max(c, 0), 64);
        const int   p2 = (c < 0) ? 65 : min(c + 1, 65);
        const float q1 = (c < 0) ? 1.0f : ((c > 63) ? 0.0f : sg);
        const float q2 = ((unsigned)c <= 63u) ? (1.0f - sg) : 0.0f;
        const int i1 = p1 * 64 + t, i2 = p2 * 64 + t;
        const float h1 = H[i1], h2 = H[i2];   // p1 != p2 always
        H[i1] = h1 + q1;
        H[i2] = h2 + q2;
    }
    __syncthreads();

    // merge 8 private copies + 8-wave parallel prefix over s
    float tot[8];
    float strip = 0.0f;
#pragma unroll
    for (int i = 0; i < 8; ++i) {
        const int s = w * 8 + i;
        float sum = 0.0f;
#pragma unroll
        for (int w2 = 0; w2 < WAVES; ++w2) sum += hist[w2][s * 64 + t];
        tot[i] = sum;
        strip += sum;
    }
    stripsum[w][t] = strip;
    __syncthreads();

    float running = 0.0f;
    for (int w2 = 0; w2 < w; ++w2) running += stripsum[w2][t];

    float* ob = out + (size_t)b * 4096;
#pragma unroll
    for (int i = 0; i < 8; ++i) {
        running += tot[i];
        ob[(w * 8 + i) * 64 + t] = running;   // coalesced, once per element
    }
}

extern "C" void kernel_launch(void* const* d_in, const int* in_sizes, int n_in,
                              void* d_out, int out_size, void* d_ws, size_t ws_size,
                              hipStream_t stream)
{
    const float* x     = (const float*)d_in[0];
    const float* v     = (const float*)d_in[1];
    const int*   batch = (const int*)d_in[3];
    float*       out   = (float*)d_out;

    const int N = in_sizes[0] / 3;          // 50000
    const int S = in_sizes[2];              // 64
    const int B = out_size / (S * 64);      // 128

    ect_fused_kernel<<<B, THREADS, 0, stream>>>(x, v, batch, out, N, B);
}